// Round 3
// baseline (302.933 us; speedup 1.0000x reference)
//
#include <hip/hip_runtime.h>
#include <hip/hip_bf16.h>
#include <math.h>

typedef unsigned short u16;
typedef __attribute__((ext_vector_type(8))) short bf16x8;
typedef __attribute__((ext_vector_type(4))) float f32x4;
typedef __attribute__((ext_vector_type(4))) unsigned short u16x4;

#define B_ 8
#define S_ 2048
#define T_ 16384
#define D_ 1024
#define H_ 16
#define EPS_ 1e-5f

__device__ __forceinline__ u16 f2bf(float f) {
    __hip_bfloat16 h = __float2bfloat16(f);
    union { __hip_bfloat16 h; u16 u; } cv; cv.h = h; return cv.u;
}
__device__ __forceinline__ float bf2f(u16 u) {
    union { u16 u; __hip_bfloat16 h; } cv; cv.u = u; return __bfloat162float(cv.h);
}

// ---------- K0a: W' = diag(rln_g[:1024])*r_w1[:1024] transposed + split bf16;
//            c1/c2 partials over all 2048 rows ----------
__global__ __launch_bounds__(256) void k0a(const float* __restrict__ rw1,
        const float* __restrict__ rlng, const float* __restrict__ rlnb,
        u16* __restrict__ whiT, u16* __restrict__ wloT,
        float* __restrict__ c1part, float* __restrict__ c2part) {
    int nb = blockIdx.x, kb = blockIdx.y;   // nb<16, kb<32
    int t = threadIdx.x;
    int nl = t & 63, kq = t >> 6;
    int n0 = nb * 64, k0 = kb * 64;
    __shared__ float ld[64][65];
    __shared__ float red[2][4][64];
    float a1 = 0.f, a2 = 0.f;
    #pragma unroll
    for (int r = 0; r < 16; ++r) {
        int kl = r * 4 + kq;
        int k = k0 + kl, n = n0 + nl;
        float w0 = rw1[(size_t)k * 1024 + n];
        ld[kl][nl] = w0;
        a1 += rlng[k] * w0;
        a2 += rlnb[k] * w0;
    }
    red[0][kq][nl] = a1;
    red[1][kq][nl] = a2;
    __syncthreads();
    if (t < 64) {
        c1part[(size_t)kb * 1024 + n0 + t] = red[0][0][t] + red[0][1][t] + red[0][2][t] + red[0][3][t];
        c2part[(size_t)kb * 1024 + n0 + t] = red[1][0][t] + red[1][1][t] + red[1][2][t] + red[1][3][t];
    }
    if (kb < 16) {
        #pragma unroll
        for (int r = 0; r < 16; ++r) {
            int nl2 = r * 4 + kq;
            int k = k0 + nl, n = n0 + nl2;
            float w0 = ld[nl][nl2] * rlng[k];
            u16 hi = f2bf(w0);
            float lo = w0 - bf2f(hi);
            whiT[(size_t)n * 1024 + k] = hi;
            wloT[(size_t)n * 1024 + k] = f2bf(lo);
        }
    }
}

// ---------- K1: pool LN pass over x; per-token sums; x -> split bf16 ----------
__global__ __launch_bounds__(256) void k1(const float* __restrict__ x,
        u16* __restrict__ xhi, u16* __restrict__ xlo,
        float* __restrict__ sx, float* __restrict__ sxx, float* __restrict__ gpart) {
    int blk = blockIdx.x;                  // 256 blocks
    int b = blk >> 5, chunk = blk & 31;
    int tid = threadIdx.x, w = tid >> 6, lane = tid & 63;
    __shared__ float lacc[4][1024];
    float acc[4][4];
    #pragma unroll
    for (int j = 0; j < 4; ++j)
        #pragma unroll
        for (int c = 0; c < 4; ++c) acc[j][c] = 0.f;

    for (int i = 0; i < 16; ++i) {
        int s = chunk * 64 + i * 4 + w;
        size_t tok = (size_t)b * S_ + s;
        size_t base = tok * D_;
        float4 v[4];
        float sum = 0.f, ssq = 0.f;
        #pragma unroll
        for (int j = 0; j < 4; ++j) {
            v[j] = *(const float4*)&x[base + j * 256 + lane * 4];
            sum += v[j].x + v[j].y + v[j].z + v[j].w;
            ssq += v[j].x * v[j].x + v[j].y * v[j].y + v[j].z * v[j].z + v[j].w * v[j].w;
        }
        #pragma unroll
        for (int m = 1; m < 64; m <<= 1) { sum += __shfl_xor(sum, m); ssq += __shfl_xor(ssq, m); }
        float mean = sum * (1.f / 1024.f);
        float var = ssq * (1.f / 1024.f) - mean * mean;
        float rstd = rsqrtf(var + EPS_);
        if (lane == 0) { sx[tok] = sum; sxx[tok] = ssq; }
        #pragma unroll
        for (int j = 0; j < 4; ++j) {
            float xs[4] = { v[j].x, v[j].y, v[j].z, v[j].w };
            u16 hs[4], ls[4];
            #pragma unroll
            for (int c = 0; c < 4; ++c) {
                acc[j][c] += (xs[c] - mean) * rstd;
                u16 h = f2bf(xs[c]);
                hs[c] = h;
                ls[c] = f2bf(xs[c] - bf2f(h));
            }
            size_t o = base + j * 256 + lane * 4;
            *(u16x4*)&xhi[o] = (u16x4){ hs[0], hs[1], hs[2], hs[3] };
            *(u16x4*)&xlo[o] = (u16x4){ ls[0], ls[1], ls[2], ls[3] };
        }
    }
    #pragma unroll
    for (int j = 0; j < 4; ++j)
        #pragma unroll
        for (int c = 0; c < 4; ++c) lacc[w][j * 256 + lane * 4 + c] = acc[j][c];
    __syncthreads();
    for (int q = 0; q < 4; ++q) {
        int n = q * 256 + tid;
        gpart[((size_t)b * 32 + chunk) * 1024 + n] =
            lacc[0][n] + lacc[1][n] + lacc[2][n] + lacc[3][n];
    }
}

// ---------- kgemv_g: fused g-vector build (reduce gpart) + split-K GEMV with inp_w ----------
// grid (4, 32), 256 threads
__global__ __launch_bounds__(256) void kgemv_g(const float* __restrict__ gpart,
        const float* __restrict__ pg, const float* __restrict__ pb,
        const float* __restrict__ W, float* __restrict__ part) {
    int t = threadIdx.x;
    int n = blockIdx.x * 256 + t;
    int k0 = blockIdx.y * 32;
    __shared__ float sg[8][32];
    {
        int b = t >> 5, k = t & 31;
        float s = 0.f;
        #pragma unroll 8
        for (int p = 0; p < 32; ++p) s += gpart[((size_t)b * 32 + p) * 1024 + k0 + k];
        sg[b][k] = s * (1.f / 2048.f) * pg[k0 + k] + pb[k0 + k];
    }
    __syncthreads();
    float acc[8] = {};
    #pragma unroll
    for (int k = 0; k < 32; ++k) {
        float wv = W[(size_t)(k0 + k) * 1024 + n];
        #pragma unroll
        for (int b = 0; b < 8; ++b) acc[b] += sg[b][k] * wv;
    }
    #pragma unroll
    for (int b = 0; b < 8; ++b)
        part[((size_t)blockIdx.y * 8 + b) * 1024 + n] = acc[b];
}

// ---------- split-K GEMV: part[kb][b][n] = sum_{k in slice} in[b][k]*scale[k]*W[k][n] ----------
__global__ __launch_bounds__(256) void kgemv_split(const float* __restrict__ in,
        const float* __restrict__ W, const float* __restrict__ scale,
        float* __restrict__ part) {
    int t = threadIdx.x;
    int n = blockIdx.x * 256 + t;
    int k0 = blockIdx.y * 32;
    __shared__ float sg[8][32];
    {
        int b = t >> 5, k = t & 31;
        float v = in[b * 1024 + k0 + k];
        if (scale) v *= scale[k0 + k];
        sg[b][k] = v;
    }
    __syncthreads();
    float acc[8] = {};
    #pragma unroll
    for (int k = 0; k < 32; ++k) {
        float wv = W[(size_t)(k0 + k) * 1024 + n];
        #pragma unroll
        for (int b = 0; b < 8; ++b) acc[b] += sg[b][k] * wv;
    }
    #pragma unroll
    for (int b = 0; b < 8; ++b)
        part[((size_t)blockIdx.y * 8 + b) * 1024 + n] = acc[b];
}

// ---------- kgemv2_f: fused xctrl reduce(+bias) + dual split-K GEMV for W_z / W_h ----------
__global__ __launch_bounds__(256) void kgemv2_f(const float* __restrict__ partIn,
        const float* __restrict__ bias,
        const float* __restrict__ Wz, const float* __restrict__ Wh,
        float* __restrict__ zpart, float* __restrict__ hpart) {
    int t = threadIdx.x;
    int n = blockIdx.x * 256 + t;
    int k0 = blockIdx.y * 32;
    __shared__ float sg[8][32];
    {
        int b = t >> 5, k = t & 31;
        float s = bias[k0 + k];
        #pragma unroll 8
        for (int p = 0; p < 32; ++p) s += partIn[((size_t)p * 8 + b) * 1024 + k0 + k];
        sg[b][k] = s;
    }
    __syncthreads();
    float az[8] = {}, ah[8] = {};
    #pragma unroll
    for (int k = 0; k < 32; ++k) {
        size_t o = (size_t)(k0 + k) * 1024 + n;
        float wz = Wz[o];
        float wh = Wh[o];
        #pragma unroll
        for (int b = 0; b < 8; ++b) { az[b] += sg[b][k] * wz; ah[b] += sg[b][k] * wh; }
    }
    #pragma unroll
    for (int b = 0; b < 8; ++b) {
        size_t o = ((size_t)blockIdx.y * 8 + b) * 1024 + n;
        zpart[o] = az[b];
        hpart[o] = ah[b];
    }
}

// ---------- k3b reduce + gate + h-LayerNorm fused (grid 8, one block per b) ----------
__global__ __launch_bounds__(256) void k3b_red_ln(const float* __restrict__ zpart,
        const float* __restrict__ hpart, const float* __restrict__ bz,
        const float* __restrict__ bh, const float* __restrict__ state,
        const float* __restrict__ lg, const float* __restrict__ lb,
        float* __restrict__ hnew, float* __restrict__ outh,
        float* __restrict__ shb, float* __restrict__ shhb) {
    int b = blockIdx.x, tid = threadIdx.x;
    int w = tid >> 6, lane = tid & 63;
    __shared__ float rbuf[4][2];
    float hp[4];
    float sum = 0.f, ssq = 0.f;
    #pragma unroll
    for (int q = 0; q < 4; ++q) {
        int n = q * 256 + tid;
        float az = bz[n], ah = bh[n];
        #pragma unroll 8
        for (int p = 0; p < 32; ++p) {
            size_t o = ((size_t)p * 8 + b) * 1024 + n;
            az += zpart[o];
            ah += hpart[o];
        }
        float z = 1.f / (1.f + expf(-az));
        float hc = tanhf(ah);
        float v = (1.f - z) * state[(size_t)b * 1024 + n] + z * hc;
        hp[q] = v; sum += v; ssq += v * v;
    }
    #pragma unroll
    for (int m = 1; m < 64; m <<= 1) { sum += __shfl_xor(sum, m); ssq += __shfl_xor(ssq, m); }
    if (lane == 0) { rbuf[w][0] = sum; rbuf[w][1] = ssq; }
    __syncthreads();
    sum = rbuf[0][0] + rbuf[1][0] + rbuf[2][0] + rbuf[3][0];
    ssq = rbuf[0][1] + rbuf[1][1] + rbuf[2][1] + rbuf[3][1];
    float mean = sum * (1.f / 1024.f);
    float var = ssq * (1.f / 1024.f) - mean * mean;
    float rstd = rsqrtf(var + EPS_);
    float s2 = 0.f, q2 = 0.f;
    #pragma unroll
    for (int q = 0; q < 4; ++q) {
        int n = q * 256 + tid;
        float h = (hp[q] - mean) * rstd * lg[n] + lb[n];
        hnew[(size_t)b * 1024 + n] = h;
        outh[(size_t)b * 1024 + n] = h;
        s2 += h; q2 += h * h;
    }
    #pragma unroll
    for (int m = 1; m < 64; m <<= 1) { s2 += __shfl_xor(s2, m); q2 += __shfl_xor(q2, m); }
    __syncthreads();
    if (lane == 0) { rbuf[w][0] = s2; rbuf[w][1] = q2; }
    __syncthreads();
    if (tid == 0) {
        shb[b] = rbuf[0][0] + rbuf[1][0] + rbuf[2][0] + rbuf[3][0];
        shhb[b] = rbuf[0][1] + rbuf[1][1] + rbuf[2][1] + rbuf[3][1];
    }
}

// ---------- K5: split-bf16 MFMA GEMM, 2-phase LDS double-buffer (BK=32),
//            fused router-LN scalars + c1/dvec/vmat reduction + GELU + partial logits ----------
__device__ __forceinline__ void gl16(const void* g, void* l) {
    __builtin_amdgcn_global_load_lds((const __attribute__((address_space(1))) void*)g,
                                     (__attribute__((address_space(3))) void*)l, 16, 0, 0);
}

__global__ __launch_bounds__(256, 1) void k5_gemm(
        const u16* __restrict__ xhi, const u16* __restrict__ xlo,
        const u16* __restrict__ whiT, const u16* __restrict__ wloT,
        const float* __restrict__ sx, const float* __restrict__ sxx,
        const float* __restrict__ shb, const float* __restrict__ shhb,
        const float* __restrict__ vpart, const float* __restrict__ c1part,
        const float* __restrict__ c2part, const float* __restrict__ rb1,
        const float* __restrict__ rw2, float* __restrict__ lpart) {
    // staging: 2 buffers x 4 planes x (128 rows x 32 u16) = 2 x 32KB = 64KB
    // epilogue reuse: shid[128][129] f32 = 66048 B
    __shared__ unsigned char smem[66048];
    float* shid = (float*)smem;

    int nb = blockIdx.x, mb = blockIdx.y;   // (8, 128)
    int tid = threadIdx.x;
    int lane = tid & 63, wid = tid >> 6;
    int wm = wid >> 1, wn = wid & 1;
    int l16 = lane & 15, lq = lane >> 4;

    f32x4 acc[4][4] = {};
    size_t aBase = (size_t)mb * 128 * 1024;
    size_t bBase = (size_t)nb * 128 * 1024;

    // stage K-step kb into buffer s (linear LDS dest per gl16 constraint)
    auto STAGE = [&](int kb, int s) {
        unsigned char* st = smem + s * 32768;
        #pragma unroll
        for (int i = 0; i < 2; ++i) {
            int chunk = tid + 256 * i;          // 512 chunks of 16B per plane
            int row = chunk >> 2, c4 = chunk & 3;
            size_t go = (size_t)row * 1024 + (size_t)kb * 32 + c4 * 8;
            int lo = chunk * 16;
            gl16(xhi + aBase + go, st + lo);
            gl16(xlo + aBase + go, st + 8192 + lo);
            gl16(whiT + bBase + go, st + 16384 + lo);
            gl16(wloT + bBase + go, st + 24576 + lo);
        }
    };

    STAGE(0, 0);
    __syncthreads();   // drains vmcnt before barrier

    int buf = 0;
    for (int kb = 0; kb < 32; ++kb) {
        if (kb < 31) STAGE(kb + 1, buf ^ 1);   // prefetch next tile (in flight across compute)
        const u16* sAh = (const u16*)(smem + buf * 32768);
        const u16* sAl = sAh + 4096;
        const u16* sBh = sAl + 4096;
        const u16* sBl = sBh + 4096;
        bf16x8 ah[4], al[4], bh[4], bl[4];
        #pragma unroll
        for (int f = 0; f < 4; ++f) {
            int ar = wm * 64 + f * 16 + l16;
            int br = wn * 64 + f * 16 + l16;
            ah[f] = *(const bf16x8*)&sAh[ar * 32 + lq * 8];
            al[f] = *(const bf16x8*)&sAl[ar * 32 + lq * 8];
            bh[f] = *(const bf16x8*)&sBh[br * 32 + lq * 8];
            bl[f] = *(const bf16x8*)&sBl[br * 32 + lq * 8];
        }
        #pragma unroll
        for (int mf = 0; mf < 4; ++mf)
            #pragma unroll
            for (int nf = 0; nf < 4; ++nf) {
                acc[mf][nf] = __builtin_amdgcn_mfma_f32_16x16x32_bf16(ah[mf], bh[nf], acc[mf][nf], 0, 0, 0);
                acc[mf][nf] = __builtin_amdgcn_mfma_f32_16x16x32_bf16(ah[mf], bl[nf], acc[mf][nf], 0, 0, 0);
                acc[mf][nf] = __builtin_amdgcn_mfma_f32_16x16x32_bf16(al[mf], bh[nf], acc[mf][nf], 0, 0, 0);
            }
        __syncthreads();   // vmcnt(0)+lgkmcnt(0) drain + barrier: next buffer ready, reads done
        buf ^= 1;
    }

    // ---- epilogue ----
    int token0 = mb * 128;
    int bidx = token0 >> 11;
    // per-column constants: vn = reduce(vmat partials), c1n, dn = c2+rb1
    float vn[4], c1n[4], dn[4];
    #pragma unroll
    for (int nf = 0; nf < 4; ++nf) {
        int n = nb * 128 + wn * 64 + nf * 16 + l16;
        float sv = 0.f, s1 = 0.f, s2 = 0.f;
        for (int p = 0; p < 32; ++p) {
            sv += vpart[((size_t)p * 8 + bidx) * 1024 + n];
            s1 += c1part[(size_t)p * 1024 + n];
            s2 += c2part[(size_t)p * 1024 + n];
        }
        vn[nf] = sv; c1n[nf] = s1; dn[nf] = s2 + rb1[n];
    }
    float sH = shb[bidx], sHH = shhb[bidx];
    #pragma unroll
    for (int mf = 0; mf < 4; ++mf) {
        #pragma unroll
        for (int r = 0; r < 4; ++r) {
            int rowl = wm * 64 + mf * 16 + lq * 4 + r;
            int tok = token0 + rowl;
            float m = (sx[tok] + sH) * (1.f / 2048.f);
            float var = (sxx[tok] + sHH) * (1.f / 2048.f) - m * m;
            float p = rsqrtf(var + EPS_);
            float q = -m * p;
            #pragma unroll
            for (int nf = 0; nf < 4; ++nf) {
                int coll = wn * 64 + nf * 16 + l16;
                float pre = p * (acc[mf][nf][r] + vn[nf]) + q * c1n[nf] + dn[nf];
                float hid = 0.5f * pre * (1.f + erff(pre * 0.70710678118f));
                shid[rowl * 129 + coll] = hid;
            }
        }
    }
    __syncthreads();

    // partial logits for this N-block: [128 tokens][16 heads]
    int r2 = tid >> 1, half = tid & 1;
    const float* w2b = rw2 + (size_t)nb * 128 * 16 + half * 8;
    float a8[8];
    #pragma unroll
    for (int h = 0; h < 8; ++h) a8[h] = 0.f;
    #pragma unroll 8
    for (int j = 0; j < 128; ++j) {
        float hv = shid[r2 * 129 + j];
        float4 w0 = *(const float4*)(w2b + (size_t)j * 16);
        float4 w1 = *(const float4*)(w2b + (size_t)j * 16 + 4);
        a8[0] += hv * w0.x; a8[1] += hv * w0.y; a8[2] += hv * w0.z; a8[3] += hv * w0.w;
        a8[4] += hv * w1.x; a8[5] += hv * w1.y; a8[6] += hv * w1.z; a8[7] += hv * w1.w;
    }
    float* lp = lpart + ((size_t)nb * T_ + token0 + r2) * 16 + half * 8;
    #pragma unroll
    for (int h = 0; h < 8; ++h) lp[h] = a8[h];
}

// ---------- K6: sum partials -> logits -> softmax -> top4 renorm -> alpha, entropy partials ----------
__global__ __launch_bounds__(256) void k6(const float* __restrict__ lpart,
        const float* __restrict__ rb2, float* __restrict__ alpha_out,
        float* __restrict__ entpart) {
    int blk = blockIdx.x;   // 1024
    int tid = threadIdx.x;
    int token = blk * 16 + (tid >> 4);
    int h = tid & 15;
    float lg = rb2[h];
    #pragma unroll
    for (int p = 0; p < 8; ++p) lg += lpart[((size_t)p * T_ + token) * 16 + h];

    float mx = lg;
    #pragma unroll
    for (int m = 1; m < 16; m <<= 1) mx = fmaxf(mx, __shfl_xor(mx, m));
    float e = expf(lg - mx);
    float sum = e;
    #pragma unroll
    for (int m = 1; m < 16; m <<= 1) sum += __shfl_xor(sum, m);
    float a0 = e / sum;

    float work = lg;
    bool sel = false;
    #pragma unroll
    for (int it = 0; it < 4; ++it) {
        float bv = work; int bi = h;
        #pragma unroll
        for (int m = 1; m < 16; m <<= 1) {
            float ov = __shfl_xor(bv, m); int oi = __shfl_xor(bi, m);
            if (ov > bv || (ov == bv && oi < bi)) { bv = ov; bi = oi; }
        }
        if (h == bi) { sel = true; work = -1e30f; }
    }
    float am = sel ? a0 : 0.f;
    float den = am;
    #pragma unroll
    for (int m = 1; m < 16; m <<= 1) den += __shfl_xor(den, m);
    den = fmaxf(den, 1e-12f);
    float a = am / den;
    alpha_out[(size_t)token * 16 + h] = a;

    float term = a * logf(fmaxf(a, 1e-12f));
    #pragma unroll
    for (int m = 1; m < 64; m <<= 1) term += __shfl_xor(term, m);
    __shared__ float tw[4];
    if ((tid & 63) == 0) tw[tid >> 6] = term;
    __syncthreads();
    if (tid == 0) entpart[blk] = tw[0] + tw[1] + tw[2] + tw[3];
}

// ---------- K7: entropy finalize ----------
__global__ __launch_bounds__(256) void k7(const float* __restrict__ entpart,
        float* __restrict__ out_ent) {
    int tid = threadIdx.x;
    float s = 0.f;
    for (int i = tid; i < 1024; i += 256) s += entpart[i];
    #pragma unroll
    for (int m = 1; m < 64; m <<= 1) s += __shfl_xor(s, m);
    __shared__ float tw[4];
    if ((tid & 63) == 0) tw[tid >> 6] = s;
    __syncthreads();
    if (tid == 0) out_ent[0] = -(tw[0] + tw[1] + tw[2] + tw[3]) * (1.f / (float)T_);
}

extern "C" void kernel_launch(void* const* d_in, const int* in_sizes, int n_in,
                              void* d_out, int out_size, void* d_ws, size_t ws_size,
                              hipStream_t stream) {
    const float* x     = (const float*)d_in[0];
    const float* state = (const float*)d_in[1];
    const float* pg    = (const float*)d_in[2];
    const float* pbv   = (const float*)d_in[3];
    const float* inpw  = (const float*)d_in[4];
    const float* inpb  = (const float*)d_in[5];
    const float* wzw   = (const float*)d_in[6];
    const float* wzb   = (const float*)d_in[7];
    const float* whw   = (const float*)d_in[8];
    const float* whb   = (const float*)d_in[9];
    const float* lnhg  = (const float*)d_in[10];
    const float* lnhb  = (const float*)d_in[11];
    const float* rlng  = (const float*)d_in[12];
    const float* rlnb  = (const float*)d_in[13];
    const float* rw1   = (const float*)d_in[14];
    const float* rb1   = (const float*)d_in[15];
    const float* rw2   = (const float*)d_in[16];
    const float* rb2   = (const float*)d_in[17];
    float* out = (float*)d_out;
    (void)in_sizes; (void)n_in; (void)out_size; (void)ws_size;

    char* base = (char*)d_ws;
    size_t off = 0;
    auto alloc = [&](size_t bytes) -> char* {
        char* p = base + off;
        off = (off + bytes + 255) & ~(size_t)255;
        return p;
    };
    u16*   xhi    = (u16*)alloc((size_t)T_ * D_ * 2);
    u16*   xlo    = (u16*)alloc((size_t)T_ * D_ * 2);
    u16*   whiT   = (u16*)alloc((size_t)D_ * D_ * 2);
    u16*   wloT   = (u16*)alloc((size_t)D_ * D_ * 2);
    float* c1part = (float*)alloc(32 * 1024 * 4);
    float* c2part = (float*)alloc(32 * 1024 * 4);
    float* sx     = (float*)alloc((size_t)T_ * 4);
    float* sxx    = (float*)alloc((size_t)T_ * 4);
    float* gpart  = (float*)alloc((size_t)8 * 32 * 1024 * 4);
    float* hnew   = (float*)alloc(8 * 1024 * 4);
    float* shb    = (float*)alloc(256);
    float* shhb   = (float*)alloc(256);
    float* lpart  = (float*)alloc((size_t)8 * T_ * H_ * 4);
    float* entpart= (float*)alloc(1024 * 4);
    float* partA  = (float*)alloc((size_t)32 * 8 * 1024 * 4);   // xctrl partials, then vmat partials
    float* partB  = (float*)alloc((size_t)32 * 8 * 1024 * 4);   // z partials
    float* partC  = (float*)alloc((size_t)32 * 8 * 1024 * 4);   // h partials

    k0a<<<dim3(16, 32), 256, 0, stream>>>(rw1, rlng, rlnb, whiT, wloT, c1part, c2part);
    k1<<<256, 256, 0, stream>>>(x, xhi, xlo, sx, sxx, gpart);
    // x_ctrl partials = (reduce gpart -> g) @ inp_w
    kgemv_g<<<dim3(4, 32), 256, 0, stream>>>(gpart, pg, pbv, inpw, partA);
    // z/h partials = (reduce partA + inp_b) @ {W_z, W_h}
    kgemv2_f<<<dim3(4, 32), 256, 0, stream>>>(partA, inpb, wzw, whw, partB, partC);
    k3b_red_ln<<<8, 256, 0, stream>>>(partB, partC, wzb, whb, state, lnhg, lnhb,
                                      hnew, out + (size_t)T_ * H_, shb, shhb);
    // vmat partials = hnew @ (rln_g[1024:] * r_w1[1024:,:])
    kgemv_split<<<dim3(4, 32), 256, 0, stream>>>(hnew, rw1 + (size_t)1024 * 1024,
                                                 rlng + 1024, partA);
    k5_gemm<<<dim3(8, 128), 256, 0, stream>>>(xhi, xlo, whiT, wloT, sx, sxx, shb, shhb,
                                              partA, c1part, c2part, rb1, rw2, lpart);
    k6<<<1024, 256, 0, stream>>>(lpart, rb2, out, entpart);
    k7<<<1, 256, 0, stream>>>(entpart, out + (size_t)T_ * H_ + (size_t)B_ * D_);
}